// Round 1
// baseline (539.452 us; speedup 1.0000x reference)
//
#include <hip/hip_runtime.h>

// GCN 2-layer + BatchNorm1d forward, f32 throughout.
// Pipeline: deg/dis -> CSR(col) -> [X1=emb@W1 * dis] -> gather-agg -> h1
//           -> [X2=h1@W2 * dis] -> gather-agg -> h2 -> batchnorm(h2)
// Self-loops handled analytically (acc starts from hs[node]).

#define EPS_BN 1e-5f

// ---------------- degree histogram ----------------
__global__ void count_k(const int* __restrict__ col, int E, int* __restrict__ cnt) {
    int e = blockIdx.x * blockDim.x + threadIdx.x;
    if (e < E) atomicAdd(&cnt[col[e]], 1);
}

// ---------------- 2-level exclusive scan (N <= 128*1024) ----------------
__global__ __launch_bounds__(1024) void scan1_k(const int* __restrict__ cnt, int n,
                                                int* __restrict__ excl, int* __restrict__ bsum) {
    __shared__ int s[1024];
    int tid = threadIdx.x;
    int i = blockIdx.x * 1024 + tid;
    int v = (i < n) ? cnt[i] : 0;
    s[tid] = v; __syncthreads();
    for (int off = 1; off < 1024; off <<= 1) {
        int t = (tid >= off) ? s[tid - off] : 0;
        __syncthreads();
        s[tid] += t;
        __syncthreads();
    }
    if (i < n) excl[i] = s[tid] - v;           // exclusive within block
    if (tid == 1023) bsum[blockIdx.x] = s[1023];
}

__global__ __launch_bounds__(128) void scan2_k(int* __restrict__ bsum, int nb) {
    __shared__ int s[128];
    int tid = threadIdx.x;
    int v = (tid < nb) ? bsum[tid] : 0;
    s[tid] = v; __syncthreads();
    for (int off = 1; off < 128; off <<= 1) {
        int t = (tid >= off) ? s[tid - off] : 0;
        __syncthreads();
        s[tid] += t;
        __syncthreads();
    }
    if (tid < nb) bsum[tid] = s[tid] - v;       // exclusive block offsets
}

__global__ __launch_bounds__(1024) void scan3_k(int* __restrict__ start, const int* __restrict__ bsum,
                                                const int* __restrict__ cnt, int* __restrict__ cursor,
                                                float* __restrict__ dis, int n, int Etot) {
    int i = blockIdx.x * 1024 + threadIdx.x;
    if (i < n) {
        int sv = start[i] + bsum[blockIdx.x];
        start[i] = sv;
        cursor[i] = sv;
        dis[i] = rsqrtf((float)(cnt[i] + 1));   // +1 self-loop; deg>=1 always
    }
    if (i == 0) start[n] = Etot;
}

// ---------------- CSR fill ----------------
__global__ void fill_k(const int* __restrict__ rowv, const int* __restrict__ colv, int E,
                       int* __restrict__ cursor, int* __restrict__ srcs) {
    int e = blockIdx.x * blockDim.x + threadIdx.x;
    if (e < E) {
        int c = colv[e];
        int p = atomicAdd(&cursor[c], 1);
        srcs[p] = rowv[e];
    }
}

// ---------------- GEMM1: [n,64] @ [64,128], epilogue *dis[row] ----------------
__global__ __launch_bounds__(512) void gemm1_k(const float* __restrict__ A, const float* __restrict__ W,
                                               const float* __restrict__ dis, float* __restrict__ out, int n) {
    __shared__ float sW[64 * 128];
    __shared__ float sA[16 * 64];
    int tid = threadIdx.x;
    for (int i = tid; i < 64 * 128; i += 512) sW[i] = W[i];
    int rowbase = blockIdx.x * 16;
    for (int i = tid; i < 16 * 64; i += 512) {
        int r = i >> 6, k = i & 63;
        int gr = rowbase + r;
        sA[i] = (gr < n) ? A[(size_t)gr * 64 + k] : 0.f;
    }
    __syncthreads();
    int r = tid >> 5, lane = tid & 31;           // 32 lanes x float4 = 128 cols
    const float4* sW4 = (const float4*)sW;
    float4 acc = make_float4(0.f, 0.f, 0.f, 0.f);
#pragma unroll 8
    for (int k = 0; k < 64; k++) {
        float a = sA[r * 64 + k];
        float4 w = sW4[k * 32 + lane];
        acc.x += a * w.x; acc.y += a * w.y; acc.z += a * w.z; acc.w += a * w.w;
    }
    int row = rowbase + r;
    if (row < n) {
        float d = dis[row];
        ((float4*)out)[(size_t)row * 32 + lane] =
            make_float4(acc.x * d, acc.y * d, acc.z * d, acc.w * d);
    }
}

// ---------------- GEMM2: [n,128] @ [128,64], epilogue *dis[row] ----------------
__global__ __launch_bounds__(256) void gemm2_k(const float* __restrict__ A, const float* __restrict__ W,
                                               const float* __restrict__ dis, float* __restrict__ out, int n) {
    __shared__ float sW[128 * 64];
    __shared__ float sA[16 * 128];
    int tid = threadIdx.x;
    for (int i = tid; i < 128 * 64; i += 256) sW[i] = W[i];
    int rowbase = blockIdx.x * 16;
    for (int i = tid; i < 16 * 128; i += 256) {
        int r = i >> 7, k = i & 127;
        int gr = rowbase + r;
        sA[i] = (gr < n) ? A[(size_t)gr * 128 + k] : 0.f;
    }
    __syncthreads();
    int r = tid >> 4, lane = tid & 15;           // 16 lanes x float4 = 64 cols
    const float4* sW4 = (const float4*)sW;
    float4 acc = make_float4(0.f, 0.f, 0.f, 0.f);
#pragma unroll 8
    for (int k = 0; k < 128; k++) {
        float a = sA[r * 128 + k];
        float4 w = sW4[k * 16 + lane];
        acc.x += a * w.x; acc.y += a * w.y; acc.z += a * w.z; acc.w += a * w.w;
    }
    int row = rowbase + r;
    if (row < n) {
        float d = dis[row];
        ((float4*)out)[(size_t)row * 16 + lane] =
            make_float4(acc.x * d, acc.y * d, acc.z * d, acc.w * d);
    }
}

// ---------------- aggregation (gather over CSR), H=128: 32 lanes/node ----------------
__global__ __launch_bounds__(256) void agg1_k(const float* __restrict__ hs, const int* __restrict__ start,
                                              const int* __restrict__ srcs, const float* __restrict__ dis,
                                              const float* __restrict__ bias, float* __restrict__ out, int n) {
    int node = blockIdx.x * 8 + (threadIdx.x >> 5);
    if (node >= n) return;
    int lane = threadIdx.x & 31;
    const float4* hs4 = (const float4*)hs;
    float4 acc = hs4[(size_t)node * 32 + lane];          // self-loop term
    int s0 = start[node], s1 = start[node + 1];
    for (int e = s0; e < s1; e++) {
        int src = srcs[e];
        float4 v = hs4[(size_t)src * 32 + lane];
        acc.x += v.x; acc.y += v.y; acc.z += v.z; acc.w += v.w;
    }
    float d = dis[node];
    float4 b = ((const float4*)bias)[lane];
    ((float4*)out)[(size_t)node * 32 + lane] =
        make_float4(acc.x * d + b.x, acc.y * d + b.y, acc.z * d + b.z, acc.w * d + b.w);
}

// ---------------- aggregation D=64: 16 lanes/node ----------------
__global__ __launch_bounds__(256) void agg2_k(const float* __restrict__ hs, const int* __restrict__ start,
                                              const int* __restrict__ srcs, const float* __restrict__ dis,
                                              const float* __restrict__ bias, float* __restrict__ out, int n) {
    int node = blockIdx.x * 16 + (threadIdx.x >> 4);
    if (node >= n) return;
    int lane = threadIdx.x & 15;
    const float4* hs4 = (const float4*)hs;
    float4 acc = hs4[(size_t)node * 16 + lane];
    int s0 = start[node], s1 = start[node + 1];
    for (int e = s0; e < s1; e++) {
        int src = srcs[e];
        float4 v = hs4[(size_t)src * 16 + lane];
        acc.x += v.x; acc.y += v.y; acc.z += v.z; acc.w += v.w;
    }
    float d = dis[node];
    float4 b = ((const float4*)bias)[lane];
    ((float4*)out)[(size_t)node * 16 + lane] =
        make_float4(acc.x * d + b.x, acc.y * d + b.y, acc.z * d + b.z, acc.w * d + b.w);
}

// ---------------- batchnorm: partial sums ----------------
__global__ __launch_bounds__(256) void bn_part_k(const float* __restrict__ x, float* __restrict__ sum,
                                                 float* __restrict__ sq, int n) {
    __shared__ float ls[256], lq[256];
    int c = threadIdx.x & 63;
    int sub = threadIdx.x >> 6;                   // 0..3
    float s = 0.f, q = 0.f;
    for (int row = blockIdx.x * 4 + sub; row < n; row += gridDim.x * 4) {
        float v = x[(size_t)row * 64 + c];
        s += v; q += v * v;
    }
    ls[threadIdx.x] = s; lq[threadIdx.x] = q;
    __syncthreads();
    if (threadIdx.x < 64) {
        s = ls[threadIdx.x] + ls[threadIdx.x + 64] + ls[threadIdx.x + 128] + ls[threadIdx.x + 192];
        q = lq[threadIdx.x] + lq[threadIdx.x + 64] + lq[threadIdx.x + 128] + lq[threadIdx.x + 192];
        atomicAdd(&sum[threadIdx.x], s);
        atomicAdd(&sq[threadIdx.x], q);
    }
}

__global__ __launch_bounds__(64) void bn_final_k(const float* __restrict__ sum, const float* __restrict__ sq,
                                                 const float* __restrict__ gamma, const float* __restrict__ beta,
                                                 int n, float* __restrict__ scale, float* __restrict__ shift) {
    int c = threadIdx.x;
    float inv_n = 1.f / (float)n;
    float mean = sum[c] * inv_n;
    float var = sq[c] * inv_n - mean * mean;      // biased variance
    float sc = gamma[c] * rsqrtf(var + EPS_BN);
    scale[c] = sc;
    shift[c] = beta[c] - mean * sc;
}

__global__ void bn_apply_k(float* __restrict__ x, const float* __restrict__ scale,
                           const float* __restrict__ shift, int total4) {
    int i = blockIdx.x * blockDim.x + threadIdx.x;
    if (i < total4) {
        float4 v = ((float4*)x)[i];
        int c = (i & 15) * 4;
        v.x = v.x * scale[c]     + shift[c];
        v.y = v.y * scale[c + 1] + shift[c + 1];
        v.z = v.z * scale[c + 2] + shift[c + 2];
        v.w = v.w * scale[c + 3] + shift[c + 3];
        ((float4*)x)[i] = v;
    }
}

extern "C" void kernel_launch(void* const* d_in, const int* in_sizes, int n_in,
                              void* d_out, int out_size, void* d_ws, size_t ws_size,
                              hipStream_t stream) {
    const float* emb   = (const float*)d_in[0];
    const float* W1    = (const float*)d_in[1];
    const float* b1    = (const float*)d_in[2];
    const float* W2    = (const float*)d_in[3];
    const float* b2    = (const float*)d_in[4];
    const float* gamma = (const float*)d_in[5];
    const float* beta  = (const float*)d_in[6];
    const int*   ei    = (const int*)d_in[7];     // [2,E] int32 per harness contract
    const int n = in_sizes[0] / 64;               // 100000
    const int E = in_sizes[7] / 2;                // 1600000
    const int* rowv = ei;                         // sources
    const int* colv = ei + E;                     // targets

    char* ws = (char*)d_ws;
    size_t o = 0;
    auto alloc = [&](size_t bytes) -> char* {
        char* p = ws + o;
        o = (o + bytes + 255) & ~(size_t)255;
        return p;
    };
    int*   cnt     = (int*)alloc((size_t)n * 4);
    int*   start   = (int*)alloc((size_t)(n + 1) * 4);
    int*   cursor  = (int*)alloc((size_t)n * 4);
    int*   bsum    = (int*)alloc(512);
    float* dis     = (float*)alloc((size_t)n * 4);
    int*   srcs    = (int*)alloc((size_t)E * 4);
    float* bnsum   = (float*)alloc(256);
    float* bnsq    = (float*)alloc(256);
    float* bnscale = (float*)alloc(256);
    float* bnshift = (float*)alloc(256);
    float* buf1    = (float*)alloc((size_t)n * 128 * 4);   // hs1, later hs2
    float* buf2    = (float*)alloc((size_t)n * 128 * 4);   // h1

    hipMemsetAsync(cnt, 0, (size_t)n * 4, stream);
    hipMemsetAsync(bnsum, 0, 512, stream);        // bnsum + bnsq (contiguous)

    const int TB = 256;
    int NB = (n + 1023) / 1024;                   // 98 <= 128

    count_k<<<(E + TB - 1) / TB, TB, 0, stream>>>(colv, E, cnt);
    scan1_k<<<NB, 1024, 0, stream>>>(cnt, n, start, bsum);
    scan2_k<<<1, 128, 0, stream>>>(bsum, NB);
    scan3_k<<<NB, 1024, 0, stream>>>(start, bsum, cnt, cursor, dis, n, E);
    fill_k<<<(E + TB - 1) / TB, TB, 0, stream>>>(rowv, colv, E, cursor, srcs);

    gemm1_k<<<(n + 15) / 16, 512, 0, stream>>>(emb, W1, dis, buf1, n);
    agg1_k<<<(n + 7) / 8, 256, 0, stream>>>(buf1, start, srcs, dis, b1, buf2, n);
    gemm2_k<<<(n + 15) / 16, 256, 0, stream>>>(buf2, W2, dis, buf1, n);
    agg2_k<<<(n + 15) / 16, 256, 0, stream>>>(buf1, start, srcs, dis, b2, (float*)d_out, n);

    bn_part_k<<<512, 256, 0, stream>>>((const float*)d_out, bnsum, bnsq, n);
    bn_final_k<<<1, 64, 0, stream>>>(bnsum, bnsq, gamma, beta, n, bnscale, bnshift);
    bn_apply_k<<<(n * 16 + TB - 1) / TB, TB, 0, stream>>>((float*)d_out, bnscale, bnshift, n * 16);
}

// Round 2
// 398.104 us; speedup vs baseline: 1.3551x; 1.3551x over previous
//
#include <hip/hip_runtime.h>

// GCN 2-layer + BatchNorm1d forward, f32 throughout.
// CSR build via 2-level bucket sort (bucket = col>>7, 128 nodes/bucket) to
// avoid the 16x HBM write amplification of random 4B scatter (R1: fill_k
// WRITE_SIZE 105MB for a 6.4MB array).
// Pipeline: histA -> bscan -> scatB(packed (row<<7)|loc) -> buildC(start,dis,srcs)
//           -> [X1=emb@W1 * dis] -> gather-agg -> h1
//           -> [X2=h1@W2 * dis] -> gather-agg -> h2 -> batchnorm(h2)
// Self-loops handled analytically (agg acc starts from hs[node]).

#define EPS_BN 1e-5f
#define NBKT_PAD 1024   // >= ceil(N/128); N=100000 -> 782 buckets

// ---------------- Pass A: bucket histogram ----------------
__global__ __launch_bounds__(256) void histA_k(const int* __restrict__ colv, int E,
                                               int* __restrict__ bcnt) {
    __shared__ int bins[NBKT_PAD];
    for (int i = threadIdx.x; i < NBKT_PAD; i += 256) bins[i] = 0;
    __syncthreads();
    for (int e = blockIdx.x * 256 + threadIdx.x; e < E; e += gridDim.x * 256)
        atomicAdd(&bins[colv[e] >> 7], 1);
    __syncthreads();
    for (int i = threadIdx.x; i < NBKT_PAD; i += 256)
        if (bins[i]) atomicAdd(&bcnt[i], bins[i]);
}

// ---------------- bucket scan (single block) ----------------
__global__ __launch_bounds__(1024) void bscan_k(const int* __restrict__ bcnt,
                                                int* __restrict__ bstart, int* __restrict__ bcur,
                                                int* __restrict__ start, int n, int E) {
    __shared__ int s[1024];
    int tid = threadIdx.x;
    int v = bcnt[tid];
    s[tid] = v; __syncthreads();
    for (int off = 1; off < 1024; off <<= 1) {
        int t = (tid >= off) ? s[tid - off] : 0;
        __syncthreads();
        s[tid] += t;
        __syncthreads();
    }
    int excl = s[tid] - v;
    bstart[tid] = excl;
    bcur[tid] = excl;
    if (tid == 1023) bstart[1024] = s[1023];
    if (tid == 0) start[n] = E;
}

// ---------------- Pass B: scatter packed edges into buckets ----------------
__global__ __launch_bounds__(256) void scatB_k(const int* __restrict__ rowv, const int* __restrict__ colv,
                                               int E, int epb, int* __restrict__ bcur,
                                               unsigned* __restrict__ ebuf) {
    __shared__ int bins[NBKT_PAD];
    int tid = threadIdx.x;
    for (int i = tid; i < NBKT_PAD; i += 256) bins[i] = 0;
    __syncthreads();
    int e0 = blockIdx.x * epb;
    int e1 = min(E, e0 + epb);
    for (int e = e0 + tid; e < e1; e += 256)
        atomicAdd(&bins[colv[e] >> 7], 1);
    __syncthreads();
    // reserve contiguous run per (block,bucket); reuse bins as write cursor
    for (int i = tid; i < NBKT_PAD; i += 256) {
        int c = bins[i];
        bins[i] = c ? atomicAdd(&bcur[i], c) : 0;
    }
    __syncthreads();
    for (int e = e0 + tid; e < e1; e += 256) {
        int c = colv[e];
        int p = atomicAdd(&bins[c >> 7], 1);
        ebuf[p] = ((unsigned)rowv[e] << 7) | (unsigned)(c & 127);
    }
}

// ---------------- Pass C: per-bucket CSR finalize ----------------
__global__ __launch_bounds__(256) void buildC_k(const unsigned* __restrict__ ebuf,
                                                const int* __restrict__ bstart,
                                                int* __restrict__ start, int* __restrict__ srcs,
                                                float* __restrict__ dis, int n) {
    __shared__ int ncnt[128], noff[128], stmp[128];
    int b = blockIdx.x;
    int tid = threadIdx.x;
    int e0 = bstart[b], e1 = bstart[b + 1];
    if (tid < 128) ncnt[tid] = 0;
    __syncthreads();
    for (int e = e0 + tid; e < e1; e += 256)
        atomicAdd(&ncnt[ebuf[e] & 127u], 1);
    __syncthreads();
    if (tid < 128) stmp[tid] = ncnt[tid];
    __syncthreads();
    for (int off = 1; off < 128; off <<= 1) {
        int t = (tid < 128 && tid >= off) ? stmp[tid - off] : 0;
        __syncthreads();
        if (tid < 128) stmp[tid] += t;
        __syncthreads();
    }
    if (tid < 128) {
        int excl = stmp[tid] - ncnt[tid];
        noff[tid] = e0 + excl;
        int node = b * 128 + tid;
        if (node < n) {
            start[node] = e0 + excl;
            dis[node] = rsqrtf((float)(ncnt[tid] + 1));   // +1 self-loop
        }
    }
    __syncthreads();
    for (int e = e0 + tid; e < e1; e += 256) {
        unsigned p = ebuf[e];
        int pos = atomicAdd(&noff[p & 127u], 1);
        srcs[pos] = (int)(p >> 7);
    }
}

// ---------------- GEMM1: [n,64] @ [64,128], epilogue *dis[row] ----------------
__global__ __launch_bounds__(512) void gemm1_k(const float* __restrict__ A, const float* __restrict__ W,
                                               const float* __restrict__ dis, float* __restrict__ out, int n) {
    __shared__ float sW[64 * 128];
    __shared__ float sA[16 * 64];
    int tid = threadIdx.x;
    for (int i = tid; i < 64 * 128; i += 512) sW[i] = W[i];
    int rowbase = blockIdx.x * 16;
    for (int i = tid; i < 16 * 64; i += 512) {
        int r = i >> 6, k = i & 63;
        int gr = rowbase + r;
        sA[i] = (gr < n) ? A[(size_t)gr * 64 + k] : 0.f;
    }
    __syncthreads();
    int r = tid >> 5, lane = tid & 31;           // 32 lanes x float4 = 128 cols
    const float4* sW4 = (const float4*)sW;
    float4 acc = make_float4(0.f, 0.f, 0.f, 0.f);
#pragma unroll 8
    for (int k = 0; k < 64; k++) {
        float a = sA[r * 64 + k];
        float4 w = sW4[k * 32 + lane];
        acc.x += a * w.x; acc.y += a * w.y; acc.z += a * w.z; acc.w += a * w.w;
    }
    int row = rowbase + r;
    if (row < n) {
        float d = dis[row];
        ((float4*)out)[(size_t)row * 32 + lane] =
            make_float4(acc.x * d, acc.y * d, acc.z * d, acc.w * d);
    }
}

// ---------------- GEMM2: [n,128] @ [128,64], epilogue *dis[row] ----------------
__global__ __launch_bounds__(256) void gemm2_k(const float* __restrict__ A, const float* __restrict__ W,
                                               const float* __restrict__ dis, float* __restrict__ out, int n) {
    __shared__ float sW[128 * 64];
    __shared__ float sA[16 * 128];
    int tid = threadIdx.x;
    for (int i = tid; i < 128 * 64; i += 256) sW[i] = W[i];
    int rowbase = blockIdx.x * 16;
    for (int i = tid; i < 16 * 128; i += 256) {
        int r = i >> 7, k = i & 127;
        int gr = rowbase + r;
        sA[i] = (gr < n) ? A[(size_t)gr * 128 + k] : 0.f;
    }
    __syncthreads();
    int r = tid >> 4, lane = tid & 15;           // 16 lanes x float4 = 64 cols
    const float4* sW4 = (const float4*)sW;
    float4 acc = make_float4(0.f, 0.f, 0.f, 0.f);
#pragma unroll 8
    for (int k = 0; k < 128; k++) {
        float a = sA[r * 128 + k];
        float4 w = sW4[k * 16 + lane];
        acc.x += a * w.x; acc.y += a * w.y; acc.z += a * w.z; acc.w += a * w.w;
    }
    int row = rowbase + r;
    if (row < n) {
        float d = dis[row];
        ((float4*)out)[(size_t)row * 16 + lane] =
            make_float4(acc.x * d, acc.y * d, acc.z * d, acc.w * d);
    }
}

// ---------------- aggregation (gather over CSR), H=128: 32 lanes/node ----------------
__global__ __launch_bounds__(256) void agg1_k(const float* __restrict__ hs, const int* __restrict__ start,
                                              const int* __restrict__ srcs, const float* __restrict__ dis,
                                              const float* __restrict__ bias, float* __restrict__ out, int n) {
    int node = blockIdx.x * 8 + (threadIdx.x >> 5);
    if (node >= n) return;
    int lane = threadIdx.x & 31;
    const float4* hs4 = (const float4*)hs;
    float4 acc = hs4[(size_t)node * 32 + lane];          // self-loop term
    int s0 = start[node], s1 = start[node + 1];
    for (int e = s0; e < s1; e++) {
        int src = srcs[e];
        float4 v = hs4[(size_t)src * 32 + lane];
        acc.x += v.x; acc.y += v.y; acc.z += v.z; acc.w += v.w;
    }
    float d = dis[node];
    float4 b = ((const float4*)bias)[lane];
    ((float4*)out)[(size_t)node * 32 + lane] =
        make_float4(acc.x * d + b.x, acc.y * d + b.y, acc.z * d + b.z, acc.w * d + b.w);
}

// ---------------- aggregation D=64: 16 lanes/node ----------------
__global__ __launch_bounds__(256) void agg2_k(const float* __restrict__ hs, const int* __restrict__ start,
                                              const int* __restrict__ srcs, const float* __restrict__ dis,
                                              const float* __restrict__ bias, float* __restrict__ out, int n) {
    int node = blockIdx.x * 16 + (threadIdx.x >> 4);
    if (node >= n) return;
    int lane = threadIdx.x & 15;
    const float4* hs4 = (const float4*)hs;
    float4 acc = hs4[(size_t)node * 16 + lane];
    int s0 = start[node], s1 = start[node + 1];
    for (int e = s0; e < s1; e++) {
        int src = srcs[e];
        float4 v = hs4[(size_t)src * 16 + lane];
        acc.x += v.x; acc.y += v.y; acc.z += v.z; acc.w += v.w;
    }
    float d = dis[node];
    float4 b = ((const float4*)bias)[lane];
    ((float4*)out)[(size_t)node * 16 + lane] =
        make_float4(acc.x * d + b.x, acc.y * d + b.y, acc.z * d + b.z, acc.w * d + b.w);
}

// ---------------- batchnorm ----------------
__global__ __launch_bounds__(256) void bn_part_k(const float* __restrict__ x, float* __restrict__ sum,
                                                 float* __restrict__ sq, int n) {
    __shared__ float ls[256], lq[256];
    int c = threadIdx.x & 63;
    int sub = threadIdx.x >> 6;                   // 0..3
    float s = 0.f, q = 0.f;
    for (int row = blockIdx.x * 4 + sub; row < n; row += gridDim.x * 4) {
        float v = x[(size_t)row * 64 + c];
        s += v; q += v * v;
    }
    ls[threadIdx.x] = s; lq[threadIdx.x] = q;
    __syncthreads();
    if (threadIdx.x < 64) {
        s = ls[threadIdx.x] + ls[threadIdx.x + 64] + ls[threadIdx.x + 128] + ls[threadIdx.x + 192];
        q = lq[threadIdx.x] + lq[threadIdx.x + 64] + lq[threadIdx.x + 128] + lq[threadIdx.x + 192];
        atomicAdd(&sum[threadIdx.x], s);
        atomicAdd(&sq[threadIdx.x], q);
    }
}

__global__ __launch_bounds__(64) void bn_final_k(const float* __restrict__ sum, const float* __restrict__ sq,
                                                 const float* __restrict__ gamma, const float* __restrict__ beta,
                                                 int n, float* __restrict__ scale, float* __restrict__ shift) {
    int c = threadIdx.x;
    float inv_n = 1.f / (float)n;
    float mean = sum[c] * inv_n;
    float var = sq[c] * inv_n - mean * mean;      // biased variance
    float sc = gamma[c] * rsqrtf(var + EPS_BN);
    scale[c] = sc;
    shift[c] = beta[c] - mean * sc;
}

__global__ void bn_apply_k(float* __restrict__ x, const float* __restrict__ scale,
                           const float* __restrict__ shift, int total4) {
    int i = blockIdx.x * blockDim.x + threadIdx.x;
    if (i < total4) {
        float4 v = ((float4*)x)[i];
        int c = (i & 15) * 4;
        v.x = v.x * scale[c]     + shift[c];
        v.y = v.y * scale[c + 1] + shift[c + 1];
        v.z = v.z * scale[c + 2] + shift[c + 2];
        v.w = v.w * scale[c + 3] + shift[c + 3];
        ((float4*)x)[i] = v;
    }
}

extern "C" void kernel_launch(void* const* d_in, const int* in_sizes, int n_in,
                              void* d_out, int out_size, void* d_ws, size_t ws_size,
                              hipStream_t stream) {
    const float* emb   = (const float*)d_in[0];
    const float* W1    = (const float*)d_in[1];
    const float* b1    = (const float*)d_in[2];
    const float* W2    = (const float*)d_in[3];
    const float* b2    = (const float*)d_in[4];
    const float* gamma = (const float*)d_in[5];
    const float* beta  = (const float*)d_in[6];
    const int*   ei    = (const int*)d_in[7];     // [2,E] int32
    const int n = in_sizes[0] / 64;               // 100000
    const int E = in_sizes[7] / 2;                // 1600000
    const int* rowv = ei;                         // sources
    const int* colv = ei + E;                     // targets
    const int NBKT = (n + 127) / 128;             // 782

    char* ws = (char*)d_ws;
    size_t o = 0;
    auto alloc = [&](size_t bytes) -> char* {
        char* p = ws + o;
        o = (o + bytes + 255) & ~(size_t)255;
        return p;
    };
    int*   bcnt    = (int*)alloc(NBKT_PAD * 4);
    int*   bstart  = (int*)alloc((NBKT_PAD + 1) * 4);
    int*   bcur    = (int*)alloc(NBKT_PAD * 4);
    int*   start   = (int*)alloc((size_t)(n + 1) * 4);
    float* dis     = (float*)alloc((size_t)n * 4);
    int*   srcs    = (int*)alloc((size_t)E * 4);
    float* bnsum   = (float*)alloc(256);
    float* bnsq    = (float*)alloc(256);
    float* bnscale = (float*)alloc(256);
    float* bnshift = (float*)alloc(256);
    float* buf1    = (float*)alloc((size_t)n * 128 * 4);   // hs1, later hs2
    float* buf2    = (float*)alloc((size_t)n * 128 * 4);   // ebuf (pre-agg1), then h1
    unsigned* ebuf = (unsigned*)buf2;             // alias: dead before agg1 writes buf2

    hipMemsetAsync(bcnt, 0, NBKT_PAD * 4, stream);
    hipMemsetAsync(bnsum, 0, 512, stream);        // bnsum + bnsq (contiguous)

    const int SCAT_B = 256;
    int epb = (E + SCAT_B - 1) / SCAT_B;

    histA_k<<<256, 256, 0, stream>>>(colv, E, bcnt);
    bscan_k<<<1, 1024, 0, stream>>>(bcnt, bstart, bcur, start, n, E);
    scatB_k<<<SCAT_B, 256, 0, stream>>>(rowv, colv, E, epb, bcur, ebuf);
    buildC_k<<<NBKT, 256, 0, stream>>>(ebuf, bstart, start, srcs, dis, n);

    gemm1_k<<<(n + 15) / 16, 512, 0, stream>>>(emb, W1, dis, buf1, n);
    agg1_k<<<(n + 7) / 8, 256, 0, stream>>>(buf1, start, srcs, dis, b1, buf2, n);
    gemm2_k<<<(n + 15) / 16, 256, 0, stream>>>(buf2, W2, dis, buf1, n);
    agg2_k<<<(n + 15) / 16, 256, 0, stream>>>(buf1, start, srcs, dis, b2, (float*)d_out, n);

    bn_part_k<<<512, 256, 0, stream>>>((const float*)d_out, bnsum, bnsq, n);
    bn_final_k<<<1, 64, 0, stream>>>(bnsum, bnsq, gamma, beta, n, bnscale, bnshift);
    bn_apply_k<<<(n * 16 + 255) / 256, 256, 0, stream>>>((float*)d_out, bnscale, bnshift, n * 16);
}

// Round 3
// 291.420 us; speedup vs baseline: 1.8511x; 1.3661x over previous
//
#include <hip/hip_runtime.h>
#include <hip/hip_fp16.h>

// GCN 2-layer + BatchNorm1d forward.
// R3: gather tables (hs1, hs2) and h1 stored fp16 (f32 accumulate everywhere)
//     to halve the irreducible per-XCD L2 miss traffic (R2: agg1 FETCH=401MB
//     = 8 XCDs x 51MB table; multiplicity-16 reuse / 8 XCDs = only 2x per-XCD
//     reuse, so bytes-per-row is the only lever). Edge loops unrolled 4x for MLP.
// CSR build via 2-level bucket sort (bucket = col>>7): histA -> bscan ->
// scatB(packed (row<<7)|loc) -> buildC(start,dis,srcs).
// Self-loops handled analytically (agg acc starts from hs[node]).

#define EPS_BN 1e-5f
#define NBKT_PAD 1024   // >= ceil(N/128); N=100000 -> 782 buckets

typedef union { ushort4 u; __half2 h[2]; } pk4_t;

// ---------------- Pass A: bucket histogram ----------------
__global__ __launch_bounds__(256) void histA_k(const int* __restrict__ colv, int E,
                                               int* __restrict__ bcnt) {
    __shared__ int bins[NBKT_PAD];
    for (int i = threadIdx.x; i < NBKT_PAD; i += 256) bins[i] = 0;
    __syncthreads();
    for (int e = blockIdx.x * 256 + threadIdx.x; e < E; e += gridDim.x * 256)
        atomicAdd(&bins[colv[e] >> 7], 1);
    __syncthreads();
    for (int i = threadIdx.x; i < NBKT_PAD; i += 256)
        if (bins[i]) atomicAdd(&bcnt[i], bins[i]);
}

// ---------------- bucket scan (single block) ----------------
__global__ __launch_bounds__(1024) void bscan_k(const int* __restrict__ bcnt,
                                                int* __restrict__ bstart, int* __restrict__ bcur,
                                                int* __restrict__ start, int n, int E) {
    __shared__ int s[1024];
    int tid = threadIdx.x;
    int v = bcnt[tid];
    s[tid] = v; __syncthreads();
    for (int off = 1; off < 1024; off <<= 1) {
        int t = (tid >= off) ? s[tid - off] : 0;
        __syncthreads();
        s[tid] += t;
        __syncthreads();
    }
    int excl = s[tid] - v;
    bstart[tid] = excl;
    bcur[tid] = excl;
    if (tid == 1023) bstart[1024] = s[1023];
    if (tid == 0) start[n] = E;
}

// ---------------- Pass B: scatter packed edges into buckets ----------------
__global__ __launch_bounds__(256) void scatB_k(const int* __restrict__ rowv, const int* __restrict__ colv,
                                               int E, int epb, int* __restrict__ bcur,
                                               unsigned* __restrict__ ebuf) {
    __shared__ int bins[NBKT_PAD];
    int tid = threadIdx.x;
    for (int i = tid; i < NBKT_PAD; i += 256) bins[i] = 0;
    __syncthreads();
    int e0 = blockIdx.x * epb;
    int e1 = min(E, e0 + epb);
    for (int e = e0 + tid; e < e1; e += 256)
        atomicAdd(&bins[colv[e] >> 7], 1);
    __syncthreads();
    for (int i = tid; i < NBKT_PAD; i += 256) {
        int c = bins[i];
        bins[i] = c ? atomicAdd(&bcur[i], c) : 0;
    }
    __syncthreads();
    for (int e = e0 + tid; e < e1; e += 256) {
        int c = colv[e];
        int p = atomicAdd(&bins[c >> 7], 1);
        ebuf[p] = ((unsigned)rowv[e] << 7) | (unsigned)(c & 127);
    }
}

// ---------------- Pass C: per-bucket CSR finalize ----------------
__global__ __launch_bounds__(256) void buildC_k(const unsigned* __restrict__ ebuf,
                                                const int* __restrict__ bstart,
                                                int* __restrict__ start, int* __restrict__ srcs,
                                                float* __restrict__ dis, int n) {
    __shared__ int ncnt[128], noff[128], stmp[128];
    int b = blockIdx.x;
    int tid = threadIdx.x;
    int e0 = bstart[b], e1 = bstart[b + 1];
    if (tid < 128) ncnt[tid] = 0;
    __syncthreads();
    for (int e = e0 + tid; e < e1; e += 256)
        atomicAdd(&ncnt[ebuf[e] & 127u], 1);
    __syncthreads();
    if (tid < 128) stmp[tid] = ncnt[tid];
    __syncthreads();
    for (int off = 1; off < 128; off <<= 1) {
        int t = (tid < 128 && tid >= off) ? stmp[tid - off] : 0;
        __syncthreads();
        if (tid < 128) stmp[tid] += t;
        __syncthreads();
    }
    if (tid < 128) {
        int excl = stmp[tid] - ncnt[tid];
        noff[tid] = e0 + excl;
        int node = b * 128 + tid;
        if (node < n) {
            start[node] = e0 + excl;
            dis[node] = rsqrtf((float)(ncnt[tid] + 1));   // +1 self-loop
        }
    }
    __syncthreads();
    for (int e = e0 + tid; e < e1; e += 256) {
        unsigned p = ebuf[e];
        int pos = atomicAdd(&noff[p & 127u], 1);
        srcs[pos] = (int)(p >> 7);
    }
}

// ---------------- GEMM1: [n,64]f32 @ [64,128]f32 -> fp16, epilogue *dis ----------------
__global__ __launch_bounds__(512) void gemm1_k(const float* __restrict__ A, const float* __restrict__ W,
                                               const float* __restrict__ dis, __half* __restrict__ out, int n) {
    __shared__ float sW[64 * 128];
    __shared__ float sA[16 * 64];
    int tid = threadIdx.x;
    for (int i = tid; i < 64 * 128; i += 512) sW[i] = W[i];
    int rowbase = blockIdx.x * 16;
    for (int i = tid; i < 16 * 64; i += 512) {
        int r = i >> 6, k = i & 63;
        int gr = rowbase + r;
        sA[i] = (gr < n) ? A[(size_t)gr * 64 + k] : 0.f;
    }
    __syncthreads();
    int r = tid >> 5, lane = tid & 31;           // 32 lanes x 4 cols = 128
    const float4* sW4 = (const float4*)sW;
    float4 acc = make_float4(0.f, 0.f, 0.f, 0.f);
#pragma unroll 8
    for (int k = 0; k < 64; k++) {
        float a = sA[r * 64 + k];
        float4 w = sW4[k * 32 + lane];
        acc.x += a * w.x; acc.y += a * w.y; acc.z += a * w.z; acc.w += a * w.w;
    }
    int row = rowbase + r;
    if (row < n) {
        float d = dis[row];
        pk4_t p;
        p.h[0] = __floats2half2_rn(acc.x * d, acc.y * d);
        p.h[1] = __floats2half2_rn(acc.z * d, acc.w * d);
        ((ushort4*)out)[(size_t)row * 32 + lane] = p.u;
    }
}

// ---------------- GEMM2: [n,128]fp16 @ [128,64]f32 -> fp16, epilogue *dis ----------------
__global__ __launch_bounds__(256) void gemm2_k(const __half* __restrict__ A, const float* __restrict__ W,
                                               const float* __restrict__ dis, __half* __restrict__ out, int n) {
    __shared__ float sW[128 * 64];
    __shared__ float sA[16 * 128];
    int tid = threadIdx.x;
    for (int i = tid; i < 128 * 64; i += 256) sW[i] = W[i];
    int rowbase = blockIdx.x * 16;
    // 16 rows x 128 halves = 2048 halves = 512 ushort4; 256 threads x 2
    for (int i = tid; i < 512; i += 256) {
        int r = i >> 5, k4 = i & 31;              // k4: group of 4 halves
        int gr = rowbase + r;
        pk4_t p;
        if (gr < n) p.u = ((const ushort4*)A)[(size_t)gr * 32 + k4];
        else p.u = make_ushort4(0, 0, 0, 0);
        float2 f0 = __half22float2(p.h[0]);
        float2 f1 = __half22float2(p.h[1]);
        float* dst = &sA[r * 128 + k4 * 4];
        dst[0] = f0.x; dst[1] = f0.y; dst[2] = f1.x; dst[3] = f1.y;
    }
    __syncthreads();
    int r = tid >> 4, lane = tid & 15;           // 16 lanes x 4 cols = 64
    const float4* sW4 = (const float4*)sW;
    float4 acc = make_float4(0.f, 0.f, 0.f, 0.f);
#pragma unroll 8
    for (int k = 0; k < 128; k++) {
        float a = sA[r * 128 + k];
        float4 w = sW4[k * 16 + lane];
        acc.x += a * w.x; acc.y += a * w.y; acc.z += a * w.z; acc.w += a * w.w;
    }
    int row = rowbase + r;
    if (row < n) {
        float d = dis[row];
        pk4_t p;
        p.h[0] = __floats2half2_rn(acc.x * d, acc.y * d);
        p.h[1] = __floats2half2_rn(acc.z * d, acc.w * d);
        ((ushort4*)out)[(size_t)row * 16 + lane] = p.u;
    }
}

__device__ __forceinline__ void acc_pk(float4& acc, ushort4 u) {
    pk4_t p; p.u = u;
    float2 f0 = __half22float2(p.h[0]);
    float2 f1 = __half22float2(p.h[1]);
    acc.x += f0.x; acc.y += f0.y; acc.z += f1.x; acc.w += f1.y;
}

// ---------------- agg1 (H=128): 32 lanes/node, fp16 in, fp16 out (+bias) ----------------
__global__ __launch_bounds__(256) void agg1_k(const __half* __restrict__ hs, const int* __restrict__ start,
                                              const int* __restrict__ srcs, const float* __restrict__ dis,
                                              const float* __restrict__ bias, __half* __restrict__ out, int n) {
    int node = blockIdx.x * 8 + (threadIdx.x >> 5);
    if (node >= n) return;
    int lane = threadIdx.x & 31;
    const ushort4* hs4 = (const ushort4*)hs;
    float4 acc = make_float4(0.f, 0.f, 0.f, 0.f);
    acc_pk(acc, hs4[(size_t)node * 32 + lane]);           // self-loop term
    int s0 = start[node], s1 = start[node + 1];
    int e = s0;
    for (; e + 3 < s1; e += 4) {
        int i0 = srcs[e], i1 = srcs[e + 1], i2 = srcs[e + 2], i3 = srcs[e + 3];
        ushort4 v0 = hs4[(size_t)i0 * 32 + lane];
        ushort4 v1 = hs4[(size_t)i1 * 32 + lane];
        ushort4 v2 = hs4[(size_t)i2 * 32 + lane];
        ushort4 v3 = hs4[(size_t)i3 * 32 + lane];
        acc_pk(acc, v0); acc_pk(acc, v1); acc_pk(acc, v2); acc_pk(acc, v3);
    }
    for (; e < s1; e++) acc_pk(acc, hs4[(size_t)srcs[e] * 32 + lane]);
    float d = dis[node];
    float4 b = ((const float4*)bias)[lane];
    pk4_t p;
    p.h[0] = __floats2half2_rn(acc.x * d + b.x, acc.y * d + b.y);
    p.h[1] = __floats2half2_rn(acc.z * d + b.z, acc.w * d + b.w);
    ((ushort4*)out)[(size_t)node * 32 + lane] = p.u;
}

// ---------------- agg2 (D=64): 16 lanes/node, fp16 in, f32 out (+bias) ----------------
__global__ __launch_bounds__(256) void agg2_k(const __half* __restrict__ hs, const int* __restrict__ start,
                                              const int* __restrict__ srcs, const float* __restrict__ dis,
                                              const float* __restrict__ bias, float* __restrict__ out, int n) {
    int node = blockIdx.x * 16 + (threadIdx.x >> 4);
    if (node >= n) return;
    int lane = threadIdx.x & 15;
    const ushort4* hs4 = (const ushort4*)hs;
    float4 acc = make_float4(0.f, 0.f, 0.f, 0.f);
    acc_pk(acc, hs4[(size_t)node * 16 + lane]);
    int s0 = start[node], s1 = start[node + 1];
    int e = s0;
    for (; e + 3 < s1; e += 4) {
        int i0 = srcs[e], i1 = srcs[e + 1], i2 = srcs[e + 2], i3 = srcs[e + 3];
        ushort4 v0 = hs4[(size_t)i0 * 16 + lane];
        ushort4 v1 = hs4[(size_t)i1 * 16 + lane];
        ushort4 v2 = hs4[(size_t)i2 * 16 + lane];
        ushort4 v3 = hs4[(size_t)i3 * 16 + lane];
        acc_pk(acc, v0); acc_pk(acc, v1); acc_pk(acc, v2); acc_pk(acc, v3);
    }
    for (; e < s1; e++) acc_pk(acc, hs4[(size_t)srcs[e] * 16 + lane]);
    float d = dis[node];
    float4 b = ((const float4*)bias)[lane];
    ((float4*)out)[(size_t)node * 16 + lane] =
        make_float4(acc.x * d + b.x, acc.y * d + b.y, acc.z * d + b.z, acc.w * d + b.w);
}

// ---------------- batchnorm ----------------
__global__ __launch_bounds__(256) void bn_part_k(const float* __restrict__ x, float* __restrict__ sum,
                                                 float* __restrict__ sq, int n) {
    __shared__ float ls[256], lq[256];
    int c = threadIdx.x & 63;
    int sub = threadIdx.x >> 6;                   // 0..3
    float s = 0.f, q = 0.f;
    for (int row = blockIdx.x * 4 + sub; row < n; row += gridDim.x * 4) {
        float v = x[(size_t)row * 64 + c];
        s += v; q += v * v;
    }
    ls[threadIdx.x] = s; lq[threadIdx.x] = q;
    __syncthreads();
    if (threadIdx.x < 64) {
        s = ls[threadIdx.x] + ls[threadIdx.x + 64] + ls[threadIdx.x + 128] + ls[threadIdx.x + 192];
        q = lq[threadIdx.x] + lq[threadIdx.x + 64] + lq[threadIdx.x + 128] + lq[threadIdx.x + 192];
        atomicAdd(&sum[threadIdx.x], s);
        atomicAdd(&sq[threadIdx.x], q);
    }
}

__global__ __launch_bounds__(64) void bn_final_k(const float* __restrict__ sum, const float* __restrict__ sq,
                                                 const float* __restrict__ gamma, const float* __restrict__ beta,
                                                 int n, float* __restrict__ scale, float* __restrict__ shift) {
    int c = threadIdx.x;
    float inv_n = 1.f / (float)n;
    float mean = sum[c] * inv_n;
    float var = sq[c] * inv_n - mean * mean;      // biased variance
    float sc = gamma[c] * rsqrtf(var + EPS_BN);
    scale[c] = sc;
    shift[c] = beta[c] - mean * sc;
}

__global__ void bn_apply_k(float* __restrict__ x, const float* __restrict__ scale,
                           const float* __restrict__ shift, int total4) {
    int i = blockIdx.x * blockDim.x + threadIdx.x;
    if (i < total4) {
        float4 v = ((float4*)x)[i];
        int c = (i & 15) * 4;
        v.x = v.x * scale[c]     + shift[c];
        v.y = v.y * scale[c + 1] + shift[c + 1];
        v.z = v.z * scale[c + 2] + shift[c + 2];
        v.w = v.w * scale[c + 3] + shift[c + 3];
        ((float4*)x)[i] = v;
    }
}

extern "C" void kernel_launch(void* const* d_in, const int* in_sizes, int n_in,
                              void* d_out, int out_size, void* d_ws, size_t ws_size,
                              hipStream_t stream) {
    const float* emb   = (const float*)d_in[0];
    const float* W1    = (const float*)d_in[1];
    const float* b1    = (const float*)d_in[2];
    const float* W2    = (const float*)d_in[3];
    const float* b2    = (const float*)d_in[4];
    const float* gamma = (const float*)d_in[5];
    const float* beta  = (const float*)d_in[6];
    const int*   ei    = (const int*)d_in[7];     // [2,E] int32
    const int n = in_sizes[0] / 64;               // 100000
    const int E = in_sizes[7] / 2;                // 1600000
    const int* rowv = ei;                         // sources
    const int* colv = ei + E;                     // targets
    const int NBKT = (n + 127) / 128;             // 782

    char* ws = (char*)d_ws;
    size_t o = 0;
    auto alloc = [&](size_t bytes) -> char* {
        char* p = ws + o;
        o = (o + bytes + 255) & ~(size_t)255;
        return p;
    };
    int*    bcnt    = (int*)alloc(NBKT_PAD * 4);
    int*    bstart  = (int*)alloc((NBKT_PAD + 1) * 4);
    int*    bcur    = (int*)alloc(NBKT_PAD * 4);
    int*    start   = (int*)alloc((size_t)(n + 1) * 4);
    float*  dis     = (float*)alloc((size_t)n * 4);
    int*    srcs    = (int*)alloc((size_t)E * 4);
    float*  bnsum   = (float*)alloc(256);
    float*  bnsq    = (float*)alloc(256);
    float*  bnscale = (float*)alloc(256);
    float*  bnshift = (float*)alloc(256);
    __half* hs1     = (__half*)alloc((size_t)n * 128 * 2);  // fp16 table (layer1)
    __half* h1      = (__half*)alloc((size_t)n * 128 * 2);  // agg1 out
    __half* hs2     = (__half*)alloc((size_t)n * 64 * 2);   // fp16 table (layer2)
    unsigned* ebuf  = (unsigned*)alloc((size_t)E * 4);      // packed bucket edges

    hipMemsetAsync(bcnt, 0, NBKT_PAD * 4, stream);
    hipMemsetAsync(bnsum, 0, 512, stream);        // bnsum + bnsq (contiguous)

    const int SCAT_B = 256;
    int epb = (E + SCAT_B - 1) / SCAT_B;

    histA_k<<<256, 256, 0, stream>>>(colv, E, bcnt);
    bscan_k<<<1, 1024, 0, stream>>>(bcnt, bstart, bcur, start, n, E);
    scatB_k<<<SCAT_B, 256, 0, stream>>>(rowv, colv, E, epb, bcur, ebuf);
    buildC_k<<<NBKT, 256, 0, stream>>>(ebuf, bstart, start, srcs, dis, n);

    gemm1_k<<<(n + 15) / 16, 512, 0, stream>>>(emb, W1, dis, hs1, n);
    agg1_k<<<(n + 7) / 8, 256, 0, stream>>>(hs1, start, srcs, dis, b1, h1, n);
    gemm2_k<<<(n + 15) / 16, 256, 0, stream>>>(h1, W2, dis, hs2, n);
    agg2_k<<<(n + 15) / 16, 256, 0, stream>>>(hs2, start, srcs, dis, b2, (float*)d_out, n);

    bn_part_k<<<512, 256, 0, stream>>>((const float*)d_out, bnsum, bnsq, n);
    bn_final_k<<<1, 64, 0, stream>>>(bnsum, bnsq, gamma, beta, n, bnscale, bnshift);
    bn_apply_k<<<(n * 16 + 255) / 256, 256, 0, stream>>>((float*)d_out, bnscale, bnshift, n * 16);
}